// Round 2
// baseline (4007.713 us; speedup 1.0000x reference)
//
#include <hip/hip_runtime.h>

// EnhancedQuantumInspiredLSTM on MI355X (gfx950).
// Round-2 fix: inputs/outputs are FP32 (reference declares jnp.float32; the
// round-1 NaN is the signature of reading fp32 mantissa halfwords as bf16 —
// uniform bits hit exponent 0xFF with p~1/256 -> NaN flood). Internal compute
// stays fp16-MFMA with fp32 accumulation/gates.
//
// Pipeline:
//   k_prep    : fp32->fp16 conversions, cos/sin tables, transposes, zero state
//   k_quantum : q = |x @ (cos + i sin)|  via fp16 MFMA, stored (S,B,H) fp16
//   k_rec     : persistent 64-WG kernel, both LSTM layers pipelined (lag 2),
//               weights resident in VGPRs, grid sync via device-scope atomic
//   k_fc      : fc1+relu+fc2 -> d_out (fp32)

typedef _Float16 f16;
typedef _Float16 f16x8 __attribute__((ext_vector_type(8)));
typedef float f32x4 __attribute__((ext_vector_type(4)));

#define MFMA16(a, b, c) __builtin_amdgcn_mfma_f32_16x16x32_f16((a), (b), (c), 0, 0, 0)

// ---- workspace layout (bytes) ----
#define OFF_Q16 0UL          // 32768*512*2   = 33,554,432
#define OFF_HS1 33554432UL   // 32768*512*2
#define OFF_X16 67108864UL   // 32768*128*2   = 8,388,608
#define OFF_W16 75497472UL   // 4*2048*512*2  = 8,388,608  [l][ih,hh]
#define OFF_COS 83886080UL   // 512*128*2     = 131,072    (transposed: [h][i])
#define OFF_SIN 84017152UL   // 131,072
#define OFF_BSUM 84148224UL  // 2*2048*4      = 16,384
#define OFF_HBUF 84164608UL  // 2*2*64*512*2  = 262,144    [layer][slot][b][j]
#define OFF_HLAST 84426752UL // 64*512*4      = 131,072
#define OFF_FC1WT 84557824UL // 512*512*4     = 1,048,576  (transposed [k][n])
#define OFF_BAR 85606400UL   // 256
#define WS_NEEDED 85606656UL

// =====================================================================
// prep: conversions / transposes / zeroing.  Flat grid-stride index space.
// =====================================================================
__global__ __launch_bounds__(256) void k_prep(
    const float* __restrict__ x, const float* __restrict__ theta,
    const float* __restrict__ phi, const float* __restrict__ thn,
    const float* __restrict__ phn, const float* __restrict__ Wih,
    const float* __restrict__ Whh, const float* __restrict__ bih,
    const float* __restrict__ bhh, const float* __restrict__ fc1w,
    f16* __restrict__ x16, f16* __restrict__ w16, f16* __restrict__ cosT,
    f16* __restrict__ sinT, float* __restrict__ bsum, float* __restrict__ fc1wT,
    f16* __restrict__ hbuf, unsigned* __restrict__ bar) {
  const int T1 = 4194304;        // x -> x16 (s,b,i) fp16
  const int T2 = T1 + 4194304;   // W_ih/W_hh -> w16 fp16
  const int T3 = T2 + 65536;     // cos/sin tables (transposed)
  const int T4 = T3 + 262144;    // fc1_w -> fc1wT fp32
  const int T5 = T4 + 4096;      // bsum
  const int T6 = T5 + 131072;    // zero hbuf
  const int T7 = T6 + 64;        // zero barrier
  for (int idx = blockIdx.x * 256 + threadIdx.x; idx < T7; idx += gridDim.x * 256) {
    if (idx < T1) {
      int s = idx >> 13, rem = idx & 8191, b = rem >> 7, i = rem & 127;
      x16[idx] = (f16)x[b * 65536 + s * 128 + i];
    } else if (idx < T2) {
      int j = idx - T1;
      if (j < 2097152) {
        int l = j >> 20, r = j & 1048575;
        w16[(size_t)(l * 2 + 0) * 1048576 + r] = (f16)Wih[j];
      } else {
        int j2 = j - 2097152;
        int l = j2 >> 20, r = j2 & 1048575;
        w16[(size_t)(l * 2 + 1) * 1048576 + r] = (f16)Whh[j2];
      }
    } else if (idx < T3) {
      int e = idx - T2;
      int i = e >> 9, h = e & 511;
      float a = theta[e] + thn[e];
      float p = phi[e] + phn[e];
      cosT[h * 128 + i] = (f16)cosf(a);
      sinT[h * 128 + i] = (f16)sinf(p);
    } else if (idx < T4) {
      int e = idx - T3;
      int n = e >> 9, k = e & 511;
      fc1wT[k * 512 + n] = fc1w[e];
    } else if (idx < T5) {
      int e = idx - T4;
      bsum[e] = bih[e] + bhh[e];
    } else if (idx < T6) {
      hbuf[idx - T5] = (f16)0.f;
    } else {
      bar[idx - T6] = 0u;
    }
  }
}

// =====================================================================
// quantum: q16[r=s*64+b][h] = sqrt((x.cos)^2 + (x.sin)^2), fp16 MFMA
// grid (512, 4), block 256 (4 waves). Tile M=64, N=128, K=128.
// =====================================================================
__global__ __launch_bounds__(256) void k_quantum(
    const f16* __restrict__ x16, const f16* __restrict__ cosT,
    const f16* __restrict__ sinT, f16* __restrict__ q16) {
  __shared__ __align__(16) f16 a_lds[64 * 136];  // pitch 136 halfs = 272 B
  const int tid = threadIdx.x;
  const int r0 = blockIdx.x * 64, h0 = blockIdx.y * 128;
#pragma unroll
  for (int g = 0; g < 4; ++g) {
    int G = g * 256 + tid, row = G >> 4, col = G & 15;
    *(uint4*)((char*)a_lds + row * 272 + col * 16) =
        *(const uint4*)(x16 + (size_t)(r0 + row) * 128 + col * 8);
  }
  __syncthreads();
  const int wv = tid >> 6, lane = tid & 63, n15 = lane & 15, quad = lane >> 4;
  const int nb = h0 + wv * 32;
  f32x4 ac[4][2], as_[4][2];
#pragma unroll
  for (int mt = 0; mt < 4; ++mt)
#pragma unroll
    for (int nt = 0; nt < 2; ++nt) {
      ac[mt][nt] = (f32x4){0.f, 0.f, 0.f, 0.f};
      as_[mt][nt] = (f32x4){0.f, 0.f, 0.f, 0.f};
    }
#pragma unroll
  for (int it = 0; it < 4; ++it) {
    f16x8 a[4];
#pragma unroll
    for (int mt = 0; mt < 4; ++mt)
      a[mt] = *(const f16x8*)((const char*)a_lds + (mt * 16 + n15) * 272 + it * 64 + quad * 16);
#pragma unroll
    for (int nt = 0; nt < 2; ++nt) {
      const f16x8 bc = *(const f16x8*)(cosT + (size_t)(nb + nt * 16 + n15) * 128 + it * 32 + quad * 8);
      const f16x8 bs = *(const f16x8*)(sinT + (size_t)(nb + nt * 16 + n15) * 128 + it * 32 + quad * 8);
#pragma unroll
      for (int mt = 0; mt < 4; ++mt) {
        ac[mt][nt] = MFMA16(a[mt], bc, ac[mt][nt]);
        as_[mt][nt] = MFMA16(a[mt], bs, as_[mt][nt]);
      }
    }
  }
#pragma unroll
  for (int mt = 0; mt < 4; ++mt)
#pragma unroll
    for (int nt = 0; nt < 2; ++nt)
#pragma unroll
      for (int r = 0; r < 4; ++r) {
        int row = r0 + mt * 16 + quad * 4 + r;  // C: row=(lane>>4)*4+reg, col=lane&15
        int col = nb + nt * 16 + n15;
        float re = ac[mt][nt][r], im = as_[mt][nt][r];
        q16[(size_t)row * 512 + col] = (f16)sqrtf(re * re + im * im);
      }
}

// =====================================================================
// recurrent persistent kernel
// =====================================================================
__device__ __forceinline__ void stage_copy(f16* stage, const f16* __restrict__ src, int tid) {
  // 64 rows x 512 halfs -> LDS, 16B granules XOR-swizzled: (c ^ (r&7))
#pragma unroll
  for (int i = 0; i < 8; ++i) {
    int G = i * 512 + tid;
    int r = G >> 6, c = G & 63;
    uint4 v = *(const uint4*)(src + (size_t)G * 8);
    *(uint4*)((char*)stage + r * 1024 + ((c ^ (r & 7)) * 16)) = v;
  }
}
__device__ __forceinline__ f16x8 lds_a(const f16* stage, int row, int it, int quad) {
  int g = (it * 4 + quad) ^ (row & 7);
  return *(const f16x8*)((const char*)stage + row * 1024 + g * 16);
}
__device__ __forceinline__ float sigf(float x) { return 1.f / (1.f + __expf(-x)); }
__device__ __forceinline__ float tanhf_fast(float x) { return 1.f - 2.f / (__expf(2.f * x) + 1.f); }

__global__ __launch_bounds__(512, 2) void k_rec(
    const f16* __restrict__ q16, f16* __restrict__ hs1, const f16* __restrict__ w16,
    const float* __restrict__ bsum, f16* __restrict__ hbuf, float* __restrict__ hlast,
    unsigned* bar) {
  __shared__ __align__(16) unsigned char smem[65536];
  f16* stage = (f16*)smem;   // 64KB stage buffer (xq, then h)
  float* gbuf = (float*)smem;  // overlaid gate buffer [b][q*16+jc], pitch 72 floats

  const int tid = threadIdx.x, lane = tid & 63, wv = tid >> 6;
  const int mv = wv & 1, qg = wv >> 1;  // mv: batch half, qg: gate type (i,f,g,o)
  const int layer = blockIdx.x >> 5, slice = blockIdx.x & 31, c0 = slice * 16;
  const int n15 = lane & 15, quad = lane >> 4;

  // resident weight fragments: Wih/Whh rows [qg*512+c0 .. +16), K=512
  f16x8 wihf[16], whhf[16];
  {
    const f16* base = w16 + (size_t)(layer * 2) * 1048576 +
                      (size_t)(qg * 512 + c0 + n15) * 512 + quad * 8;
#pragma unroll
    for (int it = 0; it < 16; ++it) {
      wihf[it] = *(const f16x8*)(base + it * 32);
      whhf[it] = *(const f16x8*)(base + 1048576 + it * 32);
    }
  }
  // elementwise assignment: thread -> (b = tid>>3, jc = (tid&7)*2 + {0,1})
  const int eb = tid >> 3, ejc = (tid & 7) * 2;
  float bb[4][2];
#pragma unroll
  for (int q = 0; q < 4; ++q)
#pragma unroll
    for (int j = 0; j < 2; ++j)
      bb[q][j] = bsum[layer * 2048 + q * 512 + c0 + ejc + j];
  float cst0 = 0.f, cst1 = 0.f;

  for (int tau = 0; tau < 514; ++tau) {
    const int t = (layer == 0) ? tau : (tau - 2);  // layer 1 lags by 2 barriers
    const bool act = (layer == 0) ? (tau < 512) : (tau >= 2);
    f32x4 acc0 = {0.f, 0.f, 0.f, 0.f}, acc1 = {0.f, 0.f, 0.f, 0.f};

    // ---- phase A: x-projection GEMM (independent of h -> before barrier) ----
    if (act) {
      const f16* src = (layer == 0 ? q16 : hs1) + (size_t)t * 32768;
      stage_copy(stage, src, tid);
    }
    __syncthreads();
    if (act) {
#pragma unroll
      for (int it = 0; it < 16; ++it) {
        f16x8 a0 = lds_a(stage, mv * 32 + n15, it, quad);
        f16x8 a1 = lds_a(stage, mv * 32 + 16 + n15, it, quad);
        acc0 = MFMA16(a0, wihf[it], acc0);
        acc1 = MFMA16(a1, wihf[it], acc1);
      }
    }
    __syncthreads();  // stage buffer free before restaging

    // ---- phase B: grid barrier (h(t-1) published by all WGs), then h GEMM ----
    if (tid == 0) {
      const unsigned target = 64u * (unsigned)tau;
      while (__hip_atomic_load(bar, __ATOMIC_RELAXED, __HIP_MEMORY_SCOPE_AGENT) < target)
        __builtin_amdgcn_s_sleep(1);
      __threadfence();  // acquire: invalidate caches before reading peers' h
    }
    __syncthreads();
    if (act) {
      const f16* hsrc = hbuf + (size_t)(layer * 2 + (t & 1)) * 32768;
      stage_copy(stage, hsrc, tid);
    }
    __syncthreads();
    if (act) {
#pragma unroll
      for (int it = 0; it < 16; ++it) {
        f16x8 a0 = lds_a(stage, mv * 32 + n15, it, quad);
        f16x8 a1 = lds_a(stage, mv * 32 + 16 + n15, it, quad);
        acc0 = MFMA16(a0, whhf[it], acc0);
        acc1 = MFMA16(a1, whhf[it], acc1);
      }
    }
    __syncthreads();  // all stage reads done before gbuf overlay writes

    // ---- phase C: gate pre-acts -> LDS ----
    if (act) {
#pragma unroll
      for (int m2 = 0; m2 < 2; ++m2)
#pragma unroll
        for (int r = 0; r < 4; ++r) {
          int b = mv * 32 + m2 * 16 + quad * 4 + r;
          gbuf[b * 72 + qg * 16 + n15] = m2 ? acc1[r] : acc0[r];
        }
    }
    __syncthreads();

    // ---- phase D: elementwise LSTM cell, publish h slice ----
    if (act) {
#pragma unroll
      for (int j = 0; j < 2; ++j) {
        int jc = ejc + j;
        const float* gb = gbuf + eb * 72 + jc;
        float gi = gb[0] + bb[0][j];
        float gf = gb[16] + bb[1][j];
        float gg = gb[32] + bb[2][j];
        float go = gb[48] + bb[3][j];
        float cprev = j ? cst1 : cst0;
        float c = sigf(gf) * cprev + sigf(gi) * tanhf_fast(gg);
        if (j) cst1 = c; else cst0 = c;
        float h = sigf(go) * tanhf_fast(c);
        f16 hh = (f16)h;
        hbuf[(size_t)(layer * 2 + ((t + 1) & 1)) * 32768 + eb * 512 + c0 + jc] = hh;
        if (layer == 0)
          hs1[(size_t)t * 32768 + eb * 512 + c0 + jc] = hh;
        else if (t == 511)
          hlast[eb * 512 + c0 + jc] = h;
      }
    }

    // ---- phase E: release + arrive ----
    if (tau < 513) {
      __syncthreads();  // drains vmcnt (stores issued) + protects gbuf reuse
      if (tid == 0) {
        __threadfence();       // make h stores device-visible
        atomicAdd(bar, 1u);    // device-scope arrive
      }
    }
  }
}

// =====================================================================
// fc head: out[b] = fc2( relu(fc1(hlast)) ), 64 blocks x 512 threads
// =====================================================================
__global__ __launch_bounds__(512) void k_fc(
    const float* __restrict__ hlast, const float* __restrict__ fc1wT,
    const float* __restrict__ fc1b, const float* __restrict__ fc2w,
    const float* __restrict__ fc2b, float* __restrict__ out) {
  __shared__ float hrow[512];
  __shared__ float red[8];
  const int b = blockIdx.x, tid = threadIdx.x;
  hrow[tid] = hlast[b * 512 + tid];
  __syncthreads();
  float acc = 0.f;
#pragma unroll 8
  for (int k = 0; k < 512; ++k) acc += hrow[k] * fc1wT[k * 512 + tid];
  float h1 = acc + fc1b[tid];
  h1 = h1 > 0.f ? h1 : 0.f;
  float v = h1 * fc2w[tid];
#pragma unroll
  for (int off = 32; off >= 1; off >>= 1) v += __shfl_down(v, off);
  if ((tid & 63) == 0) red[tid >> 6] = v;
  __syncthreads();
  if (tid == 0) {
    float s = 0.f;
#pragma unroll
    for (int w = 0; w < 8; ++w) s += red[w];
    out[b] = s + fc2b[0];
  }
}

// =====================================================================
extern "C" void kernel_launch(void* const* d_in, const int* in_sizes, int n_in,
                              void* d_out, int out_size, void* d_ws, size_t ws_size,
                              hipStream_t stream) {
  if (ws_size < WS_NEEDED) return;  // fail loudly (absmax = max|ref|)

  const float* x = (const float*)d_in[0];
  const float* theta = (const float*)d_in[1];
  const float* phi = (const float*)d_in[2];
  const float* thn = (const float*)d_in[3];
  const float* phn = (const float*)d_in[4];
  const float* Wih = (const float*)d_in[5];
  const float* Whh = (const float*)d_in[6];
  const float* bih = (const float*)d_in[7];
  const float* bhh = (const float*)d_in[8];
  const float* fc1w = (const float*)d_in[9];
  const float* fc1b = (const float*)d_in[10];
  const float* fc2w = (const float*)d_in[11];
  const float* fc2b = (const float*)d_in[12];

  char* ws = (char*)d_ws;
  f16* q16 = (f16*)(ws + OFF_Q16);
  f16* hs1 = (f16*)(ws + OFF_HS1);
  f16* x16 = (f16*)(ws + OFF_X16);
  f16* w16 = (f16*)(ws + OFF_W16);
  f16* cosT = (f16*)(ws + OFF_COS);
  f16* sinT = (f16*)(ws + OFF_SIN);
  float* bsum = (float*)(ws + OFF_BSUM);
  f16* hbuf = (f16*)(ws + OFF_HBUF);
  float* hlast = (float*)(ws + OFF_HLAST);
  float* fc1wT = (float*)(ws + OFF_FC1WT);
  unsigned* bar = (unsigned*)(ws + OFF_BAR);

  k_prep<<<2048, 256, 0, stream>>>(x, theta, phi, thn, phn, Wih, Whh, bih, bhh, fc1w,
                                   x16, w16, cosT, sinT, bsum, fc1wT, hbuf, bar);
  k_quantum<<<dim3(512, 4, 1), 256, 0, stream>>>(x16, cosT, sinT, q16);
  k_rec<<<64, 512, 0, stream>>>(q16, hs1, w16, bsum, hbuf, hlast, bar);
  k_fc<<<64, 512, 0, stream>>>(hlast, fc1wT, fc1b, fc2w, fc2b, (float*)d_out);
}

// Round 3
// 3808.054 us; speedup vs baseline: 1.0524x; 1.0524x over previous
//
#include <hip/hip_runtime.h>

// EnhancedQuantumInspiredLSTM on MI355X (gfx950).
// Round-3: replace threadfence(+full L2 wbl2/inv)+central atomicAdd barrier
// with fine-grained coherent (sc0 sc1) traffic for the shared state only
// (hbuf, hs1, flags) and a per-WG flag array polled by wave 0.
// Ordering: __syncthreads drains vmcnt(0) (write-through stores complete at
// the memory-side coherence point) before tid0 publishes the flag; consumers
// observe flags and read h with cache-bypassing loads -> no fences needed.
//
// Pipeline:
//   k_prep    : fp32->fp16 conversions, cos/sin tables, transposes, zero state
//   k_quantum : q = |x @ (cos + i sin)|  via fp16 MFMA, stored (S,B,H) fp16
//   k_rec     : persistent 64-WG kernel, both LSTM layers pipelined (lag 2),
//               weights resident in VGPRs, flag-array grid sync
//   k_fc      : fc1+relu+fc2 -> d_out (fp32)

typedef _Float16 f16;
typedef _Float16 f16x8 __attribute__((ext_vector_type(8)));
typedef float f32x4 __attribute__((ext_vector_type(4)));
typedef unsigned long long u64;

#define MFMA16(a, b, c) __builtin_amdgcn_mfma_f32_16x16x32_f16((a), (b), (c), 0, 0, 0)

// ---- workspace layout (bytes) ----
#define OFF_Q16 0UL          // 32768*512*2   = 33,554,432
#define OFF_HS1 33554432UL   // 32768*512*2
#define OFF_X16 67108864UL   // 32768*128*2   = 8,388,608
#define OFF_W16 75497472UL   // 4*2048*512*2  = 8,388,608  [l][ih,hh]
#define OFF_COS 83886080UL   // 512*128*2     = 131,072    (transposed: [h][i])
#define OFF_SIN 84017152UL   // 131,072
#define OFF_BSUM 84148224UL  // 2*2048*4      = 16,384
#define OFF_HBUF 84164608UL  // 2*2*64*512*2  = 262,144    [layer][slot][b][j]
#define OFF_HLAST 84426752UL // 64*512*4      = 131,072
#define OFF_FC1WT 84557824UL // 512*512*4     = 1,048,576  (transposed [k][n])
#define OFF_BAR 85606400UL   // 256 (64 per-WG flags)
#define WS_NEEDED 85606656UL

// =====================================================================
// prep: conversions / transposes / zeroing.  Flat grid-stride index space.
// =====================================================================
__global__ __launch_bounds__(256) void k_prep(
    const float* __restrict__ x, const float* __restrict__ theta,
    const float* __restrict__ phi, const float* __restrict__ thn,
    const float* __restrict__ phn, const float* __restrict__ Wih,
    const float* __restrict__ Whh, const float* __restrict__ bih,
    const float* __restrict__ bhh, const float* __restrict__ fc1w,
    f16* __restrict__ x16, f16* __restrict__ w16, f16* __restrict__ cosT,
    f16* __restrict__ sinT, float* __restrict__ bsum, float* __restrict__ fc1wT,
    f16* __restrict__ hbuf, unsigned* __restrict__ flags) {
  const int T1 = 4194304;        // x -> x16 (s,b,i) fp16
  const int T2 = T1 + 4194304;   // W_ih/W_hh -> w16 fp16
  const int T3 = T2 + 65536;     // cos/sin tables (transposed)
  const int T4 = T3 + 262144;    // fc1_w -> fc1wT fp32
  const int T5 = T4 + 4096;      // bsum
  const int T6 = T5 + 131072;    // zero hbuf
  const int T7 = T6 + 64;        // zero flags
  for (int idx = blockIdx.x * 256 + threadIdx.x; idx < T7; idx += gridDim.x * 256) {
    if (idx < T1) {
      int s = idx >> 13, rem = idx & 8191, b = rem >> 7, i = rem & 127;
      x16[idx] = (f16)x[b * 65536 + s * 128 + i];
    } else if (idx < T2) {
      int j = idx - T1;
      if (j < 2097152) {
        int l = j >> 20, r = j & 1048575;
        w16[(size_t)(l * 2 + 0) * 1048576 + r] = (f16)Wih[j];
      } else {
        int j2 = j - 2097152;
        int l = j2 >> 20, r = j2 & 1048575;
        w16[(size_t)(l * 2 + 1) * 1048576 + r] = (f16)Whh[j2];
      }
    } else if (idx < T3) {
      int e = idx - T2;
      int i = e >> 9, h = e & 511;
      float a = theta[e] + thn[e];
      float p = phi[e] + phn[e];
      cosT[h * 128 + i] = (f16)cosf(a);
      sinT[h * 128 + i] = (f16)sinf(p);
    } else if (idx < T4) {
      int e = idx - T3;
      int n = e >> 9, k = e & 511;
      fc1wT[k * 512 + n] = fc1w[e];
    } else if (idx < T5) {
      int e = idx - T4;
      bsum[e] = bih[e] + bhh[e];
    } else if (idx < T6) {
      hbuf[idx - T5] = (f16)0.f;
    } else {
      flags[idx - T6] = 0u;
    }
  }
}

// =====================================================================
// quantum: q16[r=s*64+b][h] = sqrt((x.cos)^2 + (x.sin)^2), fp16 MFMA
// grid (512, 4), block 256 (4 waves). Tile M=64, N=128, K=128.
// =====================================================================
__global__ __launch_bounds__(256) void k_quantum(
    const f16* __restrict__ x16, const f16* __restrict__ cosT,
    const f16* __restrict__ sinT, f16* __restrict__ q16) {
  __shared__ __align__(16) f16 a_lds[64 * 136];  // pitch 136 halfs = 272 B
  const int tid = threadIdx.x;
  const int r0 = blockIdx.x * 64, h0 = blockIdx.y * 128;
#pragma unroll
  for (int g = 0; g < 4; ++g) {
    int G = g * 256 + tid, row = G >> 4, col = G & 15;
    *(uint4*)((char*)a_lds + row * 272 + col * 16) =
        *(const uint4*)(x16 + (size_t)(r0 + row) * 128 + col * 8);
  }
  __syncthreads();
  const int wv = tid >> 6, lane = tid & 63, n15 = lane & 15, quad = lane >> 4;
  const int nb = h0 + wv * 32;
  f32x4 ac[4][2], as_[4][2];
#pragma unroll
  for (int mt = 0; mt < 4; ++mt)
#pragma unroll
    for (int nt = 0; nt < 2; ++nt) {
      ac[mt][nt] = (f32x4){0.f, 0.f, 0.f, 0.f};
      as_[mt][nt] = (f32x4){0.f, 0.f, 0.f, 0.f};
    }
#pragma unroll
  for (int it = 0; it < 4; ++it) {
    f16x8 a[4];
#pragma unroll
    for (int mt = 0; mt < 4; ++mt)
      a[mt] = *(const f16x8*)((const char*)a_lds + (mt * 16 + n15) * 272 + it * 64 + quad * 16);
#pragma unroll
    for (int nt = 0; nt < 2; ++nt) {
      const f16x8 bc = *(const f16x8*)(cosT + (size_t)(nb + nt * 16 + n15) * 128 + it * 32 + quad * 8);
      const f16x8 bs = *(const f16x8*)(sinT + (size_t)(nb + nt * 16 + n15) * 128 + it * 32 + quad * 8);
#pragma unroll
      for (int mt = 0; mt < 4; ++mt) {
        ac[mt][nt] = MFMA16(a[mt], bc, ac[mt][nt]);
        as_[mt][nt] = MFMA16(a[mt], bs, as_[mt][nt]);
      }
    }
  }
#pragma unroll
  for (int mt = 0; mt < 4; ++mt)
#pragma unroll
    for (int nt = 0; nt < 2; ++nt)
#pragma unroll
      for (int r = 0; r < 4; ++r) {
        int row = r0 + mt * 16 + quad * 4 + r;  // C: row=(lane>>4)*4+reg, col=lane&15
        int col = nb + nt * 16 + n15;
        float re = ac[mt][nt][r], im = as_[mt][nt][r];
        q16[(size_t)row * 512 + col] = (f16)sqrtf(re * re + im * im);
      }
}

// =====================================================================
// recurrent persistent kernel
// =====================================================================
__device__ __forceinline__ void stage_copy(f16* stage, const f16* __restrict__ src, int tid) {
  // 64 rows x 512 halfs -> LDS, 16B granules XOR-swizzled: (c ^ (r&7))
#pragma unroll
  for (int i = 0; i < 8; ++i) {
    int G = i * 512 + tid;
    int r = G >> 6, c = G & 63;
    uint4 v = *(const uint4*)(src + (size_t)G * 8);
    *(uint4*)((char*)stage + r * 1024 + ((c ^ (r & 7)) * 16)) = v;
  }
}
// coherent variant: sc0 sc1 loads (bypass L1/L2; coherence via memory-side L3)
__device__ __forceinline__ void stage_copy_coh(f16* stage, const f16* __restrict__ src, int tid) {
#pragma unroll
  for (int i = 0; i < 8; ++i) {
    int G = i * 512 + tid;
    int r = G >> 6, c = G & 63;
    const u64* p = (const u64*)(src + (size_t)G * 8);
    u64 lo = __hip_atomic_load(p, __ATOMIC_RELAXED, __HIP_MEMORY_SCOPE_AGENT);
    u64 hi = __hip_atomic_load(p + 1, __ATOMIC_RELAXED, __HIP_MEMORY_SCOPE_AGENT);
    char* d = (char*)stage + r * 1024 + ((c ^ (r & 7)) * 16);
    *(u64*)d = lo;
    *(u64*)(d + 8) = hi;
  }
}
__device__ __forceinline__ f16x8 lds_a(const f16* stage, int row, int it, int quad) {
  int g = (it * 4 + quad) ^ (row & 7);
  return *(const f16x8*)((const char*)stage + row * 1024 + g * 16);
}
__device__ __forceinline__ float sigf(float x) { return 1.f / (1.f + __expf(-x)); }
__device__ __forceinline__ float tanhf_fast(float x) { return 1.f - 2.f / (__expf(2.f * x) + 1.f); }

__global__ __launch_bounds__(512, 2) void k_rec(
    const f16* __restrict__ q16, f16* __restrict__ hs1, const f16* __restrict__ w16,
    const float* __restrict__ bsum, f16* __restrict__ hbuf, float* __restrict__ hlast,
    unsigned* flags) {
  __shared__ __align__(16) f16 stage[64 * 512];   // 64KB stage (xq, then h)
  float* gbuf = (float*)stage;                    // overlay: [b][g*16+jc], pitch 68

  const int tid = threadIdx.x, lane = tid & 63, wv = tid >> 6;
  const int mv = wv & 1, qg = wv >> 1;  // mv: batch half, qg: gate type (i,f,g,o)
  const int layer = blockIdx.x >> 5, slice = blockIdx.x & 31, c0 = slice * 16;
  const int n15 = lane & 15, quad = lane >> 4;

  // resident weight fragments: Wih/Whh rows [qg*512+c0 .. +16), K=512
  f16x8 wihf[16], whhf[16];
  {
    const f16* base = w16 + (size_t)(layer * 2) * 1048576 +
                      (size_t)(qg * 512 + c0 + n15) * 512 + quad * 8;
#pragma unroll
    for (int it = 0; it < 16; ++it) {
      wihf[it] = *(const f16x8*)(base + it * 32);
      whhf[it] = *(const f16x8*)(base + 1048576 + it * 32);
    }
  }
  // elementwise assignment: thread -> (b = tid>>3, jc = (tid&7)*2 + {0,1})
  const int eb = tid >> 3, ejc = (tid & 7) * 2;
  float bb[4][2];
#pragma unroll
  for (int q = 0; q < 4; ++q)
#pragma unroll
    for (int j = 0; j < 2; ++j)
      bb[q][j] = bsum[layer * 2048 + q * 512 + c0 + ejc + j];
  float cst0 = 0.f, cst1 = 0.f;

  for (int tau = 0; tau < 514; ++tau) {
    const int t = (layer == 0) ? tau : (tau - 2);  // layer 1 lags by 2 barriers
    const bool act = (layer == 0) ? (tau < 512) : (tau >= 2);
    f32x4 acc0 = {0.f, 0.f, 0.f, 0.f}, acc1 = {0.f, 0.f, 0.f, 0.f};

    // ---- phase A: x-projection GEMM (independent of h -> before poll) ----
    if (act) {
      if (layer == 0)
        stage_copy(stage, q16 + (size_t)t * 32768, tid);          // immutable, cached
      else
        stage_copy_coh(stage, hs1 + (size_t)t * 32768, tid);      // cross-WG, coherent
    }
    __syncthreads();  // s1: stage ready
    if (act) {
#pragma unroll
      for (int it = 0; it < 16; ++it) {
        f16x8 a0 = lds_a(stage, mv * 32 + n15, it, quad);
        f16x8 a1 = lds_a(stage, mv * 32 + 16 + n15, it, quad);
        acc0 = MFMA16(a0, wihf[it], acc0);
        acc1 = MFMA16(a1, wihf[it], acc1);
      }
    }
    // ---- phase B: wave 0 polls the 64 per-WG flags (overlaps other waves) ----
    if (wv == 0 && tau > 0) {
      const unsigned target = (unsigned)tau;
      while (true) {
        unsigned f = __hip_atomic_load(&flags[lane], __ATOMIC_RELAXED, __HIP_MEMORY_SCOPE_AGENT);
        if (__all((int)(f >= target))) break;
      }
    }
    __syncthreads();  // s2: poll done + phase-A stage reads done
    if (act)
      stage_copy_coh(stage, hbuf + (size_t)(layer * 2 + (t & 1)) * 32768, tid);
    __syncthreads();  // s3: h staged
    if (act) {
#pragma unroll
      for (int it = 0; it < 16; ++it) {
        f16x8 a0 = lds_a(stage, mv * 32 + n15, it, quad);
        f16x8 a1 = lds_a(stage, mv * 32 + 16 + n15, it, quad);
        acc0 = MFMA16(a0, whhf[it], acc0);
        acc1 = MFMA16(a1, whhf[it], acc1);
      }
    }
    __syncthreads();  // s4: stage reads done before gbuf overlay writes

    // ---- phase C: gate pre-acts -> LDS (pitch 68: <=2-way banks) ----
    if (act) {
#pragma unroll
      for (int m2 = 0; m2 < 2; ++m2)
#pragma unroll
        for (int r = 0; r < 4; ++r) {
          int b = mv * 32 + m2 * 16 + quad * 4 + r;
          gbuf[b * 68 + qg * 16 + n15] = m2 ? acc1[r] : acc0[r];
        }
    }
    __syncthreads();  // s5: gbuf ready

    // ---- phase D: elementwise LSTM cell, publish h slice (coherent) ----
    if (act) {
      float hv[2];
#pragma unroll
      for (int j = 0; j < 2; ++j) {
        int jc = ejc + j;
        const float* gb = gbuf + eb * 68 + jc;
        float gi = gb[0] + bb[0][j];
        float gf = gb[16] + bb[1][j];
        float gg = gb[32] + bb[2][j];
        float go = gb[48] + bb[3][j];
        float cprev = j ? cst1 : cst0;
        float c = sigf(gf) * cprev + sigf(gi) * tanhf_fast(gg);
        if (j) cst1 = c; else cst0 = c;
        hv[j] = sigf(go) * tanhf_fast(c);
      }
      union { f16 h2[2]; unsigned u; } pk;
      pk.h2[0] = (f16)hv[0];
      pk.h2[1] = (f16)hv[1];
      unsigned* hb = (unsigned*)(hbuf + (size_t)(layer * 2 + ((t + 1) & 1)) * 32768 +
                                 eb * 512 + c0 + ejc);
      __hip_atomic_store(hb, pk.u, __ATOMIC_RELAXED, __HIP_MEMORY_SCOPE_AGENT);
      if (layer == 0) {
        unsigned* hp = (unsigned*)(hs1 + (size_t)t * 32768 + eb * 512 + c0 + ejc);
        __hip_atomic_store(hp, pk.u, __ATOMIC_RELAXED, __HIP_MEMORY_SCOPE_AGENT);
      } else if (t == 511) {
        hlast[eb * 512 + c0 + ejc] = hv[0];
        hlast[eb * 512 + c0 + ejc + 1] = hv[1];
      }
    }

    // ---- phase E: arrive (syncthreads drains vmcnt -> stores are visible) ----
    if (tau < 513) {
      __syncthreads();  // s6: all write-through stores complete; gbuf reads done
      if (tid == 0)
        __hip_atomic_store(&flags[blockIdx.x], (unsigned)(tau + 1),
                           __ATOMIC_RELAXED, __HIP_MEMORY_SCOPE_AGENT);
    }
  }
}

// =====================================================================
// fc head: out[b] = fc2( relu(fc1(hlast)) ), 64 blocks x 512 threads
// =====================================================================
__global__ __launch_bounds__(512) void k_fc(
    const float* __restrict__ hlast, const float* __restrict__ fc1wT,
    const float* __restrict__ fc1b, const float* __restrict__ fc2w,
    const float* __restrict__ fc2b, float* __restrict__ out) {
  __shared__ float hrow[512];
  __shared__ float red[8];
  const int b = blockIdx.x, tid = threadIdx.x;
  hrow[tid] = hlast[b * 512 + tid];
  __syncthreads();
  float acc = 0.f;
#pragma unroll 8
  for (int k = 0; k < 512; ++k) acc += hrow[k] * fc1wT[k * 512 + tid];
  float h1 = acc + fc1b[tid];
  h1 = h1 > 0.f ? h1 : 0.f;
  float v = h1 * fc2w[tid];
#pragma unroll
  for (int off = 32; off >= 1; off >>= 1) v += __shfl_down(v, off);
  if ((tid & 63) == 0) red[tid >> 6] = v;
  __syncthreads();
  if (tid == 0) {
    float s = 0.f;
#pragma unroll
    for (int w = 0; w < 8; ++w) s += red[w];
    out[b] = s + fc2b[0];
  }
}

// =====================================================================
extern "C" void kernel_launch(void* const* d_in, const int* in_sizes, int n_in,
                              void* d_out, int out_size, void* d_ws, size_t ws_size,
                              hipStream_t stream) {
  if (ws_size < WS_NEEDED) return;  // fail loudly (absmax = max|ref|)

  const float* x = (const float*)d_in[0];
  const float* theta = (const float*)d_in[1];
  const float* phi = (const float*)d_in[2];
  const float* thn = (const float*)d_in[3];
  const float* phn = (const float*)d_in[4];
  const float* Wih = (const float*)d_in[5];
  const float* Whh = (const float*)d_in[6];
  const float* bih = (const float*)d_in[7];
  const float* bhh = (const float*)d_in[8];
  const float* fc1w = (const float*)d_in[9];
  const float* fc1b = (const float*)d_in[10];
  const float* fc2w = (const float*)d_in[11];
  const float* fc2b = (const float*)d_in[12];

  char* ws = (char*)d_ws;
  f16* q16 = (f16*)(ws + OFF_Q16);
  f16* hs1 = (f16*)(ws + OFF_HS1);
  f16* x16 = (f16*)(ws + OFF_X16);
  f16* w16 = (f16*)(ws + OFF_W16);
  f16* cosT = (f16*)(ws + OFF_COS);
  f16* sinT = (f16*)(ws + OFF_SIN);
  float* bsum = (float*)(ws + OFF_BSUM);
  f16* hbuf = (f16*)(ws + OFF_HBUF);
  float* hlast = (float*)(ws + OFF_HLAST);
  float* fc1wT = (float*)(ws + OFF_FC1WT);
  unsigned* flags = (unsigned*)(ws + OFF_BAR);

  k_prep<<<2048, 256, 0, stream>>>(x, theta, phi, thn, phn, Wih, Whh, bih, bhh, fc1w,
                                   x16, w16, cosT, sinT, bsum, fc1wT, hbuf, flags);
  k_quantum<<<dim3(512, 4, 1), 256, 0, stream>>>(x16, cosT, sinT, q16);
  k_rec<<<64, 512, 0, stream>>>(q16, hs1, w16, bsum, hbuf, hlast, flags);
  k_fc<<<64, 512, 0, stream>>>(hlast, fc1wT, fc1b, fc2w, fc2b, (float*)d_out);
}

// Round 4
// 3366.277 us; speedup vs baseline: 1.1905x; 1.1312x over previous
//
#include <hip/hip_runtime.h>

// EnhancedQuantumInspiredLSTM on MI355X (gfx950).
// Round-4: r3 post-mortem showed fence removal changed nothing (FETCH_SIZE
// 529MB unchanged, dur -5%) -> bottleneck is flag-cacheline contention (all
// flags in one 256B line hammered by 64 CUs) + serialized post-detect tail.
// Changes: per-WG flag lines (256B stride, lane-parallel poll), all waves
// poll (no poll barrier), layer-0 polls only layer-0 flags (runs ahead;
// hs1 is per-t so no reuse hazard), 128KB dynamic LDS (xstage+hstage,
// gbuf overlays xstage) cutting barriers 6->4, and issue/compute/commit
// split of the coherent h-stage to hide ~900cy L3 latency under x-MFMA.
//
// Pipeline:
//   k_prep    : fp32->fp16 conversions, cos/sin tables, transposes, zero state
//   k_quantum : q = |x @ (cos + i sin)|  via fp16 MFMA, stored (S,B,H) fp16
//   k_rec     : persistent 64-WG kernel, both LSTM layers pipelined (lag 2)
//   k_fc      : fc1+relu+fc2 -> d_out (fp32)

typedef _Float16 f16;
typedef _Float16 f16x8 __attribute__((ext_vector_type(8)));
typedef float f32x4 __attribute__((ext_vector_type(4)));
typedef unsigned long long u64;

#define MFMA16(a, b, c) __builtin_amdgcn_mfma_f32_16x16x32_f16((a), (b), (c), 0, 0, 0)

// ---- workspace layout (bytes) ----
#define OFF_Q16 0UL          // 32768*512*2   = 33,554,432
#define OFF_HS1 33554432UL   // 32768*512*2
#define OFF_X16 67108864UL   // 32768*128*2   = 8,388,608
#define OFF_W16 75497472UL   // 4*2048*512*2  = 8,388,608  [l][ih,hh]
#define OFF_COS 83886080UL   // 512*128*2     = 131,072    (transposed: [h][i])
#define OFF_SIN 84017152UL   // 131,072
#define OFF_BSUM 84148224UL  // 2*2048*4      = 16,384
#define OFF_HBUF 84164608UL  // 2*2*64*512*2  = 262,144    [layer][slot][b][j]
#define OFF_HLAST 84426752UL // 64*512*4      = 131,072
#define OFF_FC1WT 84557824UL // 512*512*4     = 1,048,576  (transposed [k][n])
#define OFF_FLG 85606400UL   // 64 flags * 256B stride = 16,384
#define WS_NEEDED 85622784UL

// =====================================================================
// prep: conversions / transposes / zeroing.  Flat grid-stride index space.
// =====================================================================
__global__ __launch_bounds__(256) void k_prep(
    const float* __restrict__ x, const float* __restrict__ theta,
    const float* __restrict__ phi, const float* __restrict__ thn,
    const float* __restrict__ phn, const float* __restrict__ Wih,
    const float* __restrict__ Whh, const float* __restrict__ bih,
    const float* __restrict__ bhh, const float* __restrict__ fc1w,
    f16* __restrict__ x16, f16* __restrict__ w16, f16* __restrict__ cosT,
    f16* __restrict__ sinT, float* __restrict__ bsum, float* __restrict__ fc1wT,
    f16* __restrict__ hbuf, unsigned* __restrict__ flags) {
  const int T1 = 4194304;        // x -> x16 (s,b,i) fp16
  const int T2 = T1 + 4194304;   // W_ih/W_hh -> w16 fp16
  const int T3 = T2 + 65536;     // cos/sin tables (transposed)
  const int T4 = T3 + 262144;    // fc1_w -> fc1wT fp32
  const int T5 = T4 + 4096;      // bsum
  const int T6 = T5 + 131072;    // zero hbuf
  const int T7 = T6 + 4096;      // zero flag region (64 * 64 dwords)
  for (int idx = blockIdx.x * 256 + threadIdx.x; idx < T7; idx += gridDim.x * 256) {
    if (idx < T1) {
      int s = idx >> 13, rem = idx & 8191, b = rem >> 7, i = rem & 127;
      x16[idx] = (f16)x[b * 65536 + s * 128 + i];
    } else if (idx < T2) {
      int j = idx - T1;
      if (j < 2097152) {
        int l = j >> 20, r = j & 1048575;
        w16[(size_t)(l * 2 + 0) * 1048576 + r] = (f16)Wih[j];
      } else {
        int j2 = j - 2097152;
        int l = j2 >> 20, r = j2 & 1048575;
        w16[(size_t)(l * 2 + 1) * 1048576 + r] = (f16)Whh[j2];
      }
    } else if (idx < T3) {
      int e = idx - T2;
      int i = e >> 9, h = e & 511;
      float a = theta[e] + thn[e];
      float p = phi[e] + phn[e];
      cosT[h * 128 + i] = (f16)cosf(a);
      sinT[h * 128 + i] = (f16)sinf(p);
    } else if (idx < T4) {
      int e = idx - T3;
      int n = e >> 9, k = e & 511;
      fc1wT[k * 512 + n] = fc1w[e];
    } else if (idx < T5) {
      int e = idx - T4;
      bsum[e] = bih[e] + bhh[e];
    } else if (idx < T6) {
      hbuf[idx - T5] = (f16)0.f;
    } else {
      flags[idx - T6] = 0u;
    }
  }
}

// =====================================================================
// quantum: q16[r=s*64+b][h] = sqrt((x.cos)^2 + (x.sin)^2), fp16 MFMA
// grid (512, 4), block 256 (4 waves). Tile M=64, N=128, K=128.
// =====================================================================
__global__ __launch_bounds__(256) void k_quantum(
    const f16* __restrict__ x16, const f16* __restrict__ cosT,
    const f16* __restrict__ sinT, f16* __restrict__ q16) {
  __shared__ __align__(16) f16 a_lds[64 * 136];  // pitch 136 halfs = 272 B
  const int tid = threadIdx.x;
  const int r0 = blockIdx.x * 64, h0 = blockIdx.y * 128;
#pragma unroll
  for (int g = 0; g < 4; ++g) {
    int G = g * 256 + tid, row = G >> 4, col = G & 15;
    *(uint4*)((char*)a_lds + row * 272 + col * 16) =
        *(const uint4*)(x16 + (size_t)(r0 + row) * 128 + col * 8);
  }
  __syncthreads();
  const int wv = tid >> 6, lane = tid & 63, n15 = lane & 15, quad = lane >> 4;
  const int nb = h0 + wv * 32;
  f32x4 ac[4][2], as_[4][2];
#pragma unroll
  for (int mt = 0; mt < 4; ++mt)
#pragma unroll
    for (int nt = 0; nt < 2; ++nt) {
      ac[mt][nt] = (f32x4){0.f, 0.f, 0.f, 0.f};
      as_[mt][nt] = (f32x4){0.f, 0.f, 0.f, 0.f};
    }
#pragma unroll
  for (int it = 0; it < 4; ++it) {
    f16x8 a[4];
#pragma unroll
    for (int mt = 0; mt < 4; ++mt)
      a[mt] = *(const f16x8*)((const char*)a_lds + (mt * 16 + n15) * 272 + it * 64 + quad * 16);
#pragma unroll
    for (int nt = 0; nt < 2; ++nt) {
      const f16x8 bc = *(const f16x8*)(cosT + (size_t)(nb + nt * 16 + n15) * 128 + it * 32 + quad * 8);
      const f16x8 bs = *(const f16x8*)(sinT + (size_t)(nb + nt * 16 + n15) * 128 + it * 32 + quad * 8);
#pragma unroll
      for (int mt = 0; mt < 4; ++mt) {
        ac[mt][nt] = MFMA16(a[mt], bc, ac[mt][nt]);
        as_[mt][nt] = MFMA16(a[mt], bs, as_[mt][nt]);
      }
    }
  }
#pragma unroll
  for (int mt = 0; mt < 4; ++mt)
#pragma unroll
    for (int nt = 0; nt < 2; ++nt)
#pragma unroll
      for (int r = 0; r < 4; ++r) {
        int row = r0 + mt * 16 + quad * 4 + r;  // C: row=(lane>>4)*4+reg, col=lane&15
        int col = nb + nt * 16 + n15;
        float re = ac[mt][nt][r], im = as_[mt][nt][r];
        q16[(size_t)row * 512 + col] = (f16)sqrtf(re * re + im * im);
      }
}

// =====================================================================
// recurrent persistent kernel
// =====================================================================
__device__ __forceinline__ void stage_copy(f16* stage, const f16* __restrict__ src, int tid) {
  // 64 rows x 512 halfs -> LDS, 16B granules XOR-swizzled: (c ^ (r&7))
#pragma unroll
  for (int i = 0; i < 8; ++i) {
    int G = i * 512 + tid;
    int r = G >> 6, c = G & 63;
    uint4 v = *(const uint4*)(src + (size_t)G * 8);
    *(uint4*)((char*)stage + r * 1024 + ((c ^ (r & 7)) * 16)) = v;
  }
}
// coherent (sc0 sc1) staging, monolithic (phase A)
__device__ __forceinline__ void stage_copy_coh(f16* stage, const f16* __restrict__ src, int tid) {
#pragma unroll
  for (int i = 0; i < 8; ++i) {
    int G = i * 512 + tid;
    int r = G >> 6, c = G & 63;
    const u64* p = (const u64*)(src + (size_t)G * 8);
    u64 lo = __hip_atomic_load(p, __ATOMIC_RELAXED, __HIP_MEMORY_SCOPE_AGENT);
    u64 hi = __hip_atomic_load(p + 1, __ATOMIC_RELAXED, __HIP_MEMORY_SCOPE_AGENT);
    char* d = (char*)stage + r * 1024 + ((c ^ (r & 7)) * 16);
    *(u64*)d = lo;
    *(u64*)(d + 8) = hi;
  }
}
// split variant: issue coherent loads into regs, commit to LDS later
__device__ __forceinline__ void issue_coh(u64* r, const f16* __restrict__ src, int tid) {
#pragma unroll
  for (int i = 0; i < 8; ++i) {
    const u64* p = (const u64*)(src + (size_t)(i * 512 + tid) * 8);
    r[2 * i] = __hip_atomic_load(p, __ATOMIC_RELAXED, __HIP_MEMORY_SCOPE_AGENT);
    r[2 * i + 1] = __hip_atomic_load(p + 1, __ATOMIC_RELAXED, __HIP_MEMORY_SCOPE_AGENT);
  }
}
__device__ __forceinline__ void commit_stage(f16* stage, const u64* r, int tid) {
#pragma unroll
  for (int i = 0; i < 8; ++i) {
    int G = i * 512 + tid;
    int row = G >> 6, c = G & 63;
    char* d = (char*)stage + row * 1024 + ((c ^ (row & 7)) * 16);
    *(u64*)d = r[2 * i];
    *(u64*)(d + 8) = r[2 * i + 1];
  }
}
__device__ __forceinline__ f16x8 lds_a(const f16* stage, int row, int it, int quad) {
  int g = (it * 4 + quad) ^ (row & 7);
  return *(const f16x8*)((const char*)stage + row * 1024 + g * 16);
}
__device__ __forceinline__ float sigf(float x) { return 1.f / (1.f + __expf(-x)); }
__device__ __forceinline__ float tanhf_fast(float x) { return 1.f - 2.f / (__expf(2.f * x) + 1.f); }

__global__ __launch_bounds__(512, 2) void k_rec(
    const f16* __restrict__ q16, f16* __restrict__ hs1, const f16* __restrict__ w16,
    const float* __restrict__ bsum, f16* __restrict__ hbuf, float* __restrict__ hlast,
    unsigned* flags) {
  extern __shared__ __align__(16) char smem[];  // 131072 B dynamic
  f16* xstage = (f16*)smem;              // 64 KB: xq tile (phase A/B/E)
  f16* hstage = (f16*)(smem + 65536);    // 64 KB: h tile (phase D/F/G)
  float* gbuf = (float*)smem;            // overlay on xstage (17.4 KB), used H/I

  const int tid = threadIdx.x, lane = tid & 63, wv = tid >> 6;
  const int mv = wv & 1, qg = wv >> 1;  // mv: batch half, qg: gate type (i,f,g,o)
  const int layer = blockIdx.x >> 5, slice = blockIdx.x & 31, c0 = slice * 16;
  const int n15 = lane & 15, quad = lane >> 4;

  // resident weight fragments: Wih/Whh rows [qg*512+c0 .. +16), K=512
  f16x8 wihf[16], whhf[16];
  {
    const f16* base = w16 + (size_t)(layer * 2) * 1048576 +
                      (size_t)(qg * 512 + c0 + n15) * 512 + quad * 8;
#pragma unroll
    for (int it = 0; it < 16; ++it) {
      wihf[it] = *(const f16x8*)(base + it * 32);
      whhf[it] = *(const f16x8*)(base + 1048576 + it * 32);
    }
  }
  // elementwise assignment: thread -> (b = tid>>3, jc = (tid&7)*2 + {0,1})
  const int eb = tid >> 3, ejc = (tid & 7) * 2;
  float bb[4][2];
#pragma unroll
  for (int q = 0; q < 4; ++q)
#pragma unroll
    for (int j = 0; j < 2; ++j)
      bb[q][j] = bsum[layer * 2048 + q * 512 + c0 + ejc + j];
  float cst0 = 0.f, cst1 = 0.f;

  // per-lane poll address: layer 0 waits only on layer-0 WGs (it can run
  // ahead; hs1 slices are per-t so no reuse hazard), layer 1 waits on all.
  const unsigned* fpoll = flags + ((layer == 0) ? (lane & 31) : lane) * 64;

  for (int tau = 0; tau < 514; ++tau) {
    const int t = (layer == 0) ? tau : (tau - 2);  // layer 1 lags by 2 barriers
    const bool act = (layer == 0) ? (tau < 512) : (tau >= 2);
    f32x4 acc0 = {0.f, 0.f, 0.f, 0.f}, acc1 = {0.f, 0.f, 0.f, 0.f};

    // ---- A: stage xq tile (validity of hs1[t] guaranteed by PREVIOUS poll) --
    if (act) {
      if (layer == 0)
        stage_copy(xstage, q16 + (size_t)t * 32768, tid);      // immutable, cached
      else
        stage_copy_coh(xstage, hs1 + (size_t)t * 32768, tid);  // cross-WG, coherent
    }
    __syncthreads();  // s1: xstage ready
    // ---- B: x-projection GEMM, first half ----
    if (act) {
#pragma unroll
      for (int it = 0; it < 8; ++it) {
        f16x8 a0 = lds_a(xstage, mv * 32 + n15, it, quad);
        f16x8 a1 = lds_a(xstage, mv * 32 + 16 + n15, it, quad);
        acc0 = MFMA16(a0, wihf[it], acc0);
        acc1 = MFMA16(a1, wihf[it], acc1);
      }
    }
    // ---- C: poll (every wave; per-WG flag cachelines, lane-parallel) ----
    if (tau > 0) {
      const unsigned target = (unsigned)tau;
      while (true) {
        unsigned f = __hip_atomic_load(fpoll, __ATOMIC_RELAXED, __HIP_MEMORY_SCOPE_AGENT);
        if (__all((int)(f >= target))) break;
        __builtin_amdgcn_s_sleep(1);
      }
    }
    // ---- D: issue coherent h loads (latency hidden under E) ----
    u64 hr[16];
    if (act)
      issue_coh(hr, hbuf + (size_t)(layer * 2 + (t & 1)) * 32768, tid);
    // ---- E: x-projection GEMM, second half ----
    if (act) {
#pragma unroll
      for (int it = 8; it < 16; ++it) {
        f16x8 a0 = lds_a(xstage, mv * 32 + n15, it, quad);
        f16x8 a1 = lds_a(xstage, mv * 32 + 16 + n15, it, quad);
        acc0 = MFMA16(a0, wihf[it], acc0);
        acc1 = MFMA16(a1, wihf[it], acc1);
      }
    }
    // ---- F: commit h regs -> hstage ----
    if (act) commit_stage(hstage, hr, tid);
    __syncthreads();  // s3: hstage ready (also: E's xstage reads done -> gbuf safe)
    // ---- G: recurrent GEMM ----
    if (act) {
#pragma unroll
      for (int it = 0; it < 16; ++it) {
        f16x8 a0 = lds_a(hstage, mv * 32 + n15, it, quad);
        f16x8 a1 = lds_a(hstage, mv * 32 + 16 + n15, it, quad);
        acc0 = MFMA16(a0, whhf[it], acc0);
        acc1 = MFMA16(a1, whhf[it], acc1);
      }
    }
    // ---- H: gate pre-acts -> gbuf (xstage overlay; pitch 68: <=2-way banks) --
    if (act) {
#pragma unroll
      for (int m2 = 0; m2 < 2; ++m2)
#pragma unroll
        for (int r = 0; r < 4; ++r) {
          int b = mv * 32 + m2 * 16 + quad * 4 + r;
          gbuf[b * 68 + qg * 16 + n15] = m2 ? acc1[r] : acc0[r];
        }
    }
    __syncthreads();  // s5: gbuf ready

    // ---- I: elementwise LSTM cell, publish h slice (coherent) ----
    if (act) {
      float hv[2];
#pragma unroll
      for (int j = 0; j < 2; ++j) {
        int jc = ejc + j;
        const float* gb = gbuf + eb * 68 + jc;
        float gi = gb[0] + bb[0][j];
        float gf = gb[16] + bb[1][j];
        float gg = gb[32] + bb[2][j];
        float go = gb[48] + bb[3][j];
        float cprev = j ? cst1 : cst0;
        float c = sigf(gf) * cprev + sigf(gi) * tanhf_fast(gg);
        if (j) cst1 = c; else cst0 = c;
        hv[j] = sigf(go) * tanhf_fast(c);
      }
      union { f16 h2[2]; unsigned u; } pk;
      pk.h2[0] = (f16)hv[0];
      pk.h2[1] = (f16)hv[1];
      unsigned* hb = (unsigned*)(hbuf + (size_t)(layer * 2 + ((t + 1) & 1)) * 32768 +
                                 eb * 512 + c0 + ejc);
      __hip_atomic_store(hb, pk.u, __ATOMIC_RELAXED, __HIP_MEMORY_SCOPE_AGENT);
      if (layer == 0) {
        unsigned* hp = (unsigned*)(hs1 + (size_t)t * 32768 + eb * 512 + c0 + ejc);
        __hip_atomic_store(hp, pk.u, __ATOMIC_RELAXED, __HIP_MEMORY_SCOPE_AGENT);
      } else if (t == 511) {
        hlast[eb * 512 + c0 + ejc] = hv[0];
        hlast[eb * 512 + c0 + ejc + 1] = hv[1];
      }
    }

    // ---- J: arrive (syncthreads drains vmcnt -> stores visible at L3) ----
    if (tau < 513) {
      __syncthreads();  // s6: write-through stores complete; gbuf reads done
      if (tid == 0)
        __hip_atomic_store(&flags[(size_t)blockIdx.x * 64], (unsigned)(tau + 1),
                           __ATOMIC_RELAXED, __HIP_MEMORY_SCOPE_AGENT);
    }
  }
}

// =====================================================================
// fc head: out[b] = fc2( relu(fc1(hlast)) ), 64 blocks x 512 threads
// =====================================================================
__global__ __launch_bounds__(512) void k_fc(
    const float* __restrict__ hlast, const float* __restrict__ fc1wT,
    const float* __restrict__ fc1b, const float* __restrict__ fc2w,
    const float* __restrict__ fc2b, float* __restrict__ out) {
  __shared__ float hrow[512];
  __shared__ float red[8];
  const int b = blockIdx.x, tid = threadIdx.x;
  hrow[tid] = hlast[b * 512 + tid];
  __syncthreads();
  float acc = 0.f;
#pragma unroll 8
  for (int k = 0; k < 512; ++k) acc += hrow[k] * fc1wT[k * 512 + tid];
  float h1 = acc + fc1b[tid];
  h1 = h1 > 0.f ? h1 : 0.f;
  float v = h1 * fc2w[tid];
#pragma unroll
  for (int off = 32; off >= 1; off >>= 1) v += __shfl_down(v, off);
  if ((tid & 63) == 0) red[tid >> 6] = v;
  __syncthreads();
  if (tid == 0) {
    float s = 0.f;
#pragma unroll
    for (int w = 0; w < 8; ++w) s += red[w];
    out[b] = s + fc2b[0];
  }
}

// =====================================================================
extern "C" void kernel_launch(void* const* d_in, const int* in_sizes, int n_in,
                              void* d_out, int out_size, void* d_ws, size_t ws_size,
                              hipStream_t stream) {
  if (ws_size < WS_NEEDED) return;  // fail loudly (absmax = max|ref|)

  const float* x = (const float*)d_in[0];
  const float* theta = (const float*)d_in[1];
  const float* phi = (const float*)d_in[2];
  const float* thn = (const float*)d_in[3];
  const float* phn = (const float*)d_in[4];
  const float* Wih = (const float*)d_in[5];
  const float* Whh = (const float*)d_in[6];
  const float* bih = (const float*)d_in[7];
  const float* bhh = (const float*)d_in[8];
  const float* fc1w = (const float*)d_in[9];
  const float* fc1b = (const float*)d_in[10];
  const float* fc2w = (const float*)d_in[11];
  const float* fc2b = (const float*)d_in[12];

  char* ws = (char*)d_ws;
  f16* q16 = (f16*)(ws + OFF_Q16);
  f16* hs1 = (f16*)(ws + OFF_HS1);
  f16* x16 = (f16*)(ws + OFF_X16);
  f16* w16 = (f16*)(ws + OFF_W16);
  f16* cosT = (f16*)(ws + OFF_COS);
  f16* sinT = (f16*)(ws + OFF_SIN);
  float* bsum = (float*)(ws + OFF_BSUM);
  f16* hbuf = (f16*)(ws + OFF_HBUF);
  float* hlast = (float*)(ws + OFF_HLAST);
  float* fc1wT = (float*)(ws + OFF_FC1WT);
  unsigned* flags = (unsigned*)(ws + OFF_FLG);

  static bool attr_set = false;  // host-side only; not stream/capture state
  if (!attr_set) {
    hipFuncSetAttribute((const void*)k_rec,
                        hipFuncAttributeMaxDynamicSharedMemorySize, 131072);
    attr_set = true;
  }

  k_prep<<<2048, 256, 0, stream>>>(x, theta, phi, thn, phn, Wih, Whh, bih, bhh, fc1w,
                                   x16, w16, cosT, sinT, bsum, fc1wT, hbuf, flags);
  k_quantum<<<dim3(512, 4, 1), 256, 0, stream>>>(x16, cosT, sinT, q16);
  k_rec<<<64, 512, 131072, stream>>>(q16, hs1, w16, bsum, hbuf, hlast, flags);
  k_fc<<<64, 512, 0, stream>>>(hlast, fc1wT, fc1b, fc2w, fc2b, (float*)d_out);
}